// Round 10
// baseline (884.090 us; speedup 1.0000x reference)
//
#include <hip/hip_runtime.h>
#include <stdint.h>

#define HID 256

typedef __bf16 bf16x8 __attribute__((ext_vector_type(8)));
typedef float  f32x4  __attribute__((ext_vector_type(4)));
typedef unsigned int uint4v __attribute__((ext_vector_type(4)));

__device__ __forceinline__ unsigned short f2bf(float f){
  unsigned int x = __float_as_uint(f);
  x += 0x7FFFu + ((x >> 16) & 1u);      // RNE
  return (unsigned short)(x >> 16);
}
__device__ __forceinline__ float bflo(unsigned int x){ return __uint_as_float(x << 16); }
__device__ __forceinline__ float bfhi(unsigned int x){ return __uint_as_float(x & 0xFFFF0000u); }

// ---------------- CSR build ----------------
__global__ void count_kernel(const int* __restrict__ ei, int E, int* __restrict__ deg){
  int e = blockIdx.x*256 + threadIdx.x;
  if (e < E) atomicAdd(&deg[ei[E + e]], 1);
}

__global__ void dinv_kernel(const int* __restrict__ deg, float* __restrict__ dinv, int N){
  int i = blockIdx.x*256 + threadIdx.x;
  if (i < N) dinv[i] = 1.0f / sqrtf((float)(deg[i] + 1));   // +1 self loop
}

__global__ void scan1_kernel(const int* __restrict__ deg, int* __restrict__ rowptr,
                             int* __restrict__ partials, int N){
  __shared__ int sm[256];
  int t = threadIdx.x;
  int i = blockIdx.x*256 + t;
  int v = (i < N) ? deg[i] : 0;
  int acc = v;
  sm[t] = acc;
  __syncthreads();
  for (int off = 1; off < 256; off <<= 1){
    int add = (t >= off) ? sm[t - off] : 0;
    __syncthreads();
    acc += add;
    sm[t] = acc;
    __syncthreads();
  }
  if (i < N) rowptr[i] = acc - v;                 // exclusive, block-local
  if (t == 255) partials[blockIdx.x] = acc;       // block total
}

__global__ void scan2_kernel(int* __restrict__ partials, int nb){
  __shared__ int sm[256];
  int t = threadIdx.x;
  int v = (t < nb) ? partials[t] : 0;
  int acc = v;
  sm[t] = acc;
  __syncthreads();
  for (int off = 1; off < 256; off <<= 1){
    int add = (t >= off) ? sm[t - off] : 0;
    __syncthreads();
    acc += add;
    sm[t] = acc;
    __syncthreads();
  }
  if (t < nb) partials[t] = acc - v;              // exclusive block offsets
}

__global__ void scan3_kernel(int* __restrict__ rowptr, const int* __restrict__ partials,
                             int N, int E){
  int i = blockIdx.x*256 + threadIdx.x;
  if (i < N) rowptr[i] += partials[blockIdx.x];
  if (i == 0) rowptr[N] = E;
}

// builds interleaved edge metadata ew[p] = (src, wgt)
__global__ void scatter_kernel(const int* __restrict__ ei, int E, const int* __restrict__ rowptr,
                               int* __restrict__ fill, const float* __restrict__ dinv,
                               int2* __restrict__ ew){
  int e = blockIdx.x*256 + threadIdx.x;
  if (e >= E) return;
  int s = ei[e];
  int d = ei[E + e];
  int p = rowptr[d] + atomicAdd(&fill[d], 1);
  int2 v; v.x = s; v.y = __float_as_int(dinv[s] * dinv[d]);
  ew[p] = v;
}

// ---------------- x (f32) -> xb (bf16), 8 elems/thread ----------------
__global__ void convX_kernel(const float* __restrict__ x, unsigned short* __restrict__ xb, int total8){
  int t = blockIdx.x*256 + threadIdx.x;
  if (t >= total8) return;
  const float* p = x + (size_t)t*8;
  f32x4 a = *(const f32x4*)p;
  f32x4 b = *(const f32x4*)(p + 4);
  ushort4 o0, o1;
  o0.x = f2bf(a[0]); o0.y = f2bf(a[1]); o0.z = f2bf(a[2]); o0.w = f2bf(a[3]);
  o1.x = f2bf(b[0]); o1.y = f2bf(b[1]); o1.z = f2bf(b[2]); o1.w = f2bf(b[3]);
  ushort4* qq = (ushort4*)(xb + (size_t)t*8);
  qq[0] = o0; qq[1] = o1;
}

// ---------------- W -> W^T bf16 ----------------
// m=0: natural K order. m=1,2: K permuted by pi(p) to match gemm1's packed
// H layout: pi(p) = (p&~63) | ((p&3)<<4) | ((p>>2)&15).
__global__ void convW_kernel(const float* __restrict__ W1, const float* __restrict__ Wmu,
                             const float* __restrict__ Wls, unsigned short* __restrict__ Wt){
  int t = blockIdx.x*256 + threadIdx.x;
  if (t >= 3*65536) return;
  int m = t >> 16;
  int r = t & 0xFFFF;
  int n = r >> 8, k = r & 255;
  int ksrc = (m == 0) ? k : ((k & ~63) | ((k & 3) << 4) | ((k >> 2) & 15));
  const float* W = (m == 0) ? W1 : (m == 1 ? Wmu : Wls);
  Wt[t] = f2bf(W[ksrc*HID + n]);                  // Wt[m][n][k] = W[pi(k)][n]
}

// ---- XCD-sliced aggregation: slice = bid%8 (round-robin XCD), 32 cols/slice ----
// Per-XCD gather working set = N*64B = 3.2MB -> L2-resident. One wave per
// (node, slice); quarter q handles neighbor j+q (16 lanes x 2 cols each).
// Output SLICED: Y[slice*N*32 + node*32 + c].
__global__ void agg_slice(const unsigned short* __restrict__ X, unsigned short* __restrict__ Y,
                          const int* __restrict__ rowptr, const int2* __restrict__ ew,
                          const float* __restrict__ dinv, int N, int sin){
  int slice = blockIdx.x & 7;
  int w = ((blockIdx.x >> 3) << 2) + (threadIdx.x >> 6);
  if (w >= N) return;
  int lane = threadIdx.x & 63;
  int q = lane >> 4, cl = lane & 15;
  const unsigned short* Xs = X + slice*32 + cl*2;
  float a0 = 0.f, a1 = 0.f;
  int p0 = rowptr[w], p1 = rowptr[w+1];
  for (int base = p0; base < p1; base += 64){
    int idx = base + lane;
    int sc = 0; float wc = 0.f;
    if (idx < p1){ int2 e = ew[idx]; sc = e.x; wc = __int_as_float(e.y); }
    int cnt = min(p1 - base, 64);
    int j = 0;
    for (; j + 8 <= cnt; j += 8){          // 2 gathers in flight
      int   s0 = __shfl(sc, j + q),     s1 = __shfl(sc, j + 4 + q);
      float f0 = __shfl(wc, j + q),     f1 = __shfl(wc, j + 4 + q);
      unsigned int u0 = *(const unsigned int*)(Xs + (size_t)s0*sin);
      unsigned int u1 = *(const unsigned int*)(Xs + (size_t)s1*sin);
      a0 = fmaf(bflo(u0), f0, a0); a1 = fmaf(bfhi(u0), f0, a1);
      a0 = fmaf(bflo(u1), f1, a0); a1 = fmaf(bfhi(u1), f1, a1);
    }
    for (; j < cnt; j += 4){
      int   s = __shfl(sc, j + q);
      float f = __shfl(wc, j + q);
      unsigned int u = *(const unsigned int*)(Xs + (size_t)s*sin);
      a0 = fmaf(bflo(u), f, a0); a1 = fmaf(bfhi(u), f, a1);
    }
  }
  a0 += __shfl_xor(a0, 16); a1 += __shfl_xor(a1, 16);
  a0 += __shfl_xor(a0, 32); a1 += __shfl_xor(a1, 32);
  if (q == 0){
    float s2 = dinv[w]; s2 *= s2;          // self loop
    unsigned int u = *(const unsigned int*)(Xs + (size_t)w*sin);
    a0 = fmaf(bflo(u), s2, a0); a1 = fmaf(bfhi(u), s2, a1);
    unsigned int o = (unsigned int)f2bf(a0) | ((unsigned int)f2bf(a1) << 16);
    *(unsigned int*)(Y + (size_t)slice*N*32 + (size_t)w*32 + cl*2) = o;
  }
}

// ---- r9 full-row agg (fallback for a2 when ws can't hold packed sliced a2) ----
__global__ void agg_full(const unsigned short* __restrict__ X, unsigned short* __restrict__ Y,
                         const int* __restrict__ rowptr, const int2* __restrict__ ew,
                         const float* __restrict__ dinv, int N, int sin, int sout){
  int w = (blockIdx.x * blockDim.x + threadIdx.x) >> 6;
  int lane = threadIdx.x & 63;
  if (w >= N) return;
  int q  = lane >> 4;
  int cl = lane & 15;
  float acc[16];
  #pragma unroll
  for (int k = 0; k < 16; ++k) acc[k] = 0.f;
  int p0 = rowptr[w], p1 = rowptr[w+1];
  for (int base = p0; base < p1; base += 64){
    int idx = base + lane;
    int sc = 0; float wc = 0.f;
    if (idx < p1){ int2 e = ew[idx]; sc = e.x; wc = __int_as_float(e.y); }
    int cnt = min(p1 - base, 64);
    for (int j = 0; j < cnt; j += 4){
      int   s = __shfl(sc, j + q);
      float f = __shfl(wc, j + q);
      const unsigned short* rp = X + (size_t)s*sin + cl*16;
      uint4v u0 = *(const uint4v*)rp;
      uint4v u1 = *(const uint4v*)(rp + 8);
      acc[ 0]=fmaf(bflo(u0.x),f,acc[ 0]); acc[ 1]=fmaf(bfhi(u0.x),f,acc[ 1]);
      acc[ 2]=fmaf(bflo(u0.y),f,acc[ 2]); acc[ 3]=fmaf(bfhi(u0.y),f,acc[ 3]);
      acc[ 4]=fmaf(bflo(u0.z),f,acc[ 4]); acc[ 5]=fmaf(bfhi(u0.z),f,acc[ 5]);
      acc[ 6]=fmaf(bflo(u0.w),f,acc[ 6]); acc[ 7]=fmaf(bfhi(u0.w),f,acc[ 7]);
      acc[ 8]=fmaf(bflo(u1.x),f,acc[ 8]); acc[ 9]=fmaf(bfhi(u1.x),f,acc[ 9]);
      acc[10]=fmaf(bflo(u1.y),f,acc[10]); acc[11]=fmaf(bfhi(u1.y),f,acc[11]);
      acc[12]=fmaf(bflo(u1.z),f,acc[12]); acc[13]=fmaf(bfhi(u1.z),f,acc[13]);
      acc[14]=fmaf(bflo(u1.w),f,acc[14]); acc[15]=fmaf(bfhi(u1.w),f,acc[15]);
    }
  }
  #pragma unroll
  for (int k = 0; k < 16; ++k){
    acc[k] += __shfl_xor(acc[k], 16);
    acc[k] += __shfl_xor(acc[k], 32);
  }
  if (q == 0){
    float s2 = dinv[w]; s2 *= s2;
    const unsigned short* rp = X + (size_t)w*sin + cl*16;
    uint4v u0 = *(const uint4v*)rp;
    uint4v u1 = *(const uint4v*)(rp + 8);
    acc[ 0]=fmaf(bflo(u0.x),s2,acc[ 0]); acc[ 1]=fmaf(bfhi(u0.x),s2,acc[ 1]);
    acc[ 2]=fmaf(bflo(u0.y),s2,acc[ 2]); acc[ 3]=fmaf(bfhi(u0.y),s2,acc[ 3]);
    acc[ 4]=fmaf(bflo(u0.z),s2,acc[ 4]); acc[ 5]=fmaf(bfhi(u0.z),s2,acc[ 5]);
    acc[ 6]=fmaf(bflo(u0.w),s2,acc[ 6]); acc[ 7]=fmaf(bfhi(u0.w),s2,acc[ 7]);
    acc[ 8]=fmaf(bflo(u1.x),s2,acc[ 8]); acc[ 9]=fmaf(bfhi(u1.x),s2,acc[ 9]);
    acc[10]=fmaf(bflo(u1.y),s2,acc[10]); acc[11]=fmaf(bfhi(u1.y),s2,acc[11]);
    acc[12]=fmaf(bflo(u1.z),s2,acc[12]); acc[13]=fmaf(bfhi(u1.z),s2,acc[13]);
    acc[14]=fmaf(bflo(u1.w),s2,acc[14]); acc[15]=fmaf(bfhi(u1.w),s2,acc[15]);
    uint4v o0, o1;
    o0.x = (unsigned int)f2bf(acc[ 0]) | ((unsigned int)f2bf(acc[ 1]) << 16);
    o0.y = (unsigned int)f2bf(acc[ 2]) | ((unsigned int)f2bf(acc[ 3]) << 16);
    o0.z = (unsigned int)f2bf(acc[ 4]) | ((unsigned int)f2bf(acc[ 5]) << 16);
    o0.w = (unsigned int)f2bf(acc[ 6]) | ((unsigned int)f2bf(acc[ 7]) << 16);
    o1.x = (unsigned int)f2bf(acc[ 8]) | ((unsigned int)f2bf(acc[ 9]) << 16);
    o1.y = (unsigned int)f2bf(acc[10]) | ((unsigned int)f2bf(acc[11]) << 16);
    o1.z = (unsigned int)f2bf(acc[12]) | ((unsigned int)f2bf(acc[13]) << 16);
    o1.w = (unsigned int)f2bf(acc[14]) | ((unsigned int)f2bf(acc[15]) << 16);
    uint4v* yp = (uint4v*)(Y + (size_t)w*sout + cl*16);
    yp[0] = o0; yp[1] = o1;
  }
}

// ---------------- GEMM 1: h = relu(a1 @ W1 + b1); A SLICED, bf16 out ----------------
// H stored PERMUTED: position p = nw*64+lr*4+j holds column nw*64+j*16+lr.
__global__ __launch_bounds__(256, 8) void gemm1_kernel(const unsigned short* __restrict__ A,
    const unsigned short* __restrict__ Bt, const float* __restrict__ bias,
    unsigned short* __restrict__ H, int N){
  int r0 = blockIdx.x * 32;
  int lane = threadIdx.x & 63;
  int nw = threadIdx.x >> 6;
  int lr = lane & 15, kg = lane >> 4;
  size_t sl = (size_t)N * 32;
  f32x4 acc[2][4] = {};
  for (int ks = 0; ks < 8; ++ks){
    int kb = ks*32 + kg*8;
    bf16x8 af[2];
    #pragma unroll
    for (int rf = 0; rf < 2; ++rf){
      int row = r0 + rf*16 + lr; if (row > N-1) row = N-1;
      af[rf] = *(const bf16x8*)(A + (size_t)ks*sl + (size_t)row*32 + kg*8);
    }
    #pragma unroll
    for (int cf = 0; cf < 4; ++cf){
      int c = nw*64 + cf*16 + lr;
      bf16x8 bfr = *(const bf16x8*)(Bt + (size_t)c*HID + kb);
      acc[0][cf] = __builtin_amdgcn_mfma_f32_16x16x32_bf16(af[0], bfr, acc[0][cf], 0, 0, 0);
      acc[1][cf] = __builtin_amdgcn_mfma_f32_16x16x32_bf16(af[1], bfr, acc[1][cf], 0, 0, 0);
    }
  }
  float bv[4];
  #pragma unroll
  for (int cf = 0; cf < 4; ++cf) bv[cf] = bias[nw*64 + cf*16 + lr];
  #pragma unroll
  for (int rf = 0; rf < 2; ++rf){
    #pragma unroll
    for (int i = 0; i < 4; ++i){
      int row = r0 + rf*16 + kg*4 + i;
      if (row < N){
        ushort4 o;
        o.x = f2bf(fmaxf(acc[rf][0][i] + bv[0], 0.0f));
        o.y = f2bf(fmaxf(acc[rf][1][i] + bv[1], 0.0f));
        o.z = f2bf(fmaxf(acc[rf][2][i] + bv[2], 0.0f));
        o.w = f2bf(fmaxf(acc[rf][3][i] + bv[3], 0.0f));
        *(ushort4*)(H + (size_t)row*HID + nw*64 + lr*4) = o;
      }
    }
  }
}

// ---- eps: JAX PARTITIONABLE threefry2x32 (key=(0,1)) + XLA erfinv ----
__device__ __forceinline__ unsigned int rotl32(unsigned int v, int r){
  return (v << r) | (v >> (32 - r));
}

__device__ __forceinline__ float gauss_eps(unsigned int idxv){
  unsigned int x0 = 0u, x1 = idxv;
  const unsigned int ks0 = 0u, ks1 = 1u, ks2 = 0x1BD11BDAu ^ 0u ^ 1u;
  x0 += ks0; x1 += ks1;
#define TFR(r) { x0 += x1; x1 = rotl32(x1, r); x1 ^= x0; }
  TFR(13) TFR(15) TFR(26) TFR(6)   x0 += ks1; x1 += ks2 + 1u;
  TFR(17) TFR(29) TFR(16) TFR(24)  x0 += ks2; x1 += ks0 + 2u;
  TFR(13) TFR(15) TFR(26) TFR(6)   x0 += ks0; x1 += ks1 + 3u;
  TFR(17) TFR(29) TFR(16) TFR(24)  x0 += ks1; x1 += ks2 + 4u;
  TFR(13) TFR(15) TFR(26) TFR(6)   x0 += ks2; x1 += ks0 + 5u;
#undef TFR
  unsigned int bits = x0 ^ x1;                                   // 32-bit fold
  float f = __uint_as_float((bits >> 9) | 0x3F800000u) - 1.0f;   // [0,1)
  const float lo = -0.99999994f;                                  // nextafter(-1,0)
  float u = fmaxf(lo, fmaf(f, 2.0f, lo));                         // (hi-lo)==2.0f exactly
  float t = fmaf(-u, u, 1.0f);
  float wv = -0.69314718056f * __builtin_amdgcn_logf(t);
  float p;
  if (wv < 5.0f){
    wv -= 2.5f;
    p = 2.81022636e-08f;
    p = fmaf(p, wv, 3.43273939e-07f);
    p = fmaf(p, wv, -3.5233877e-06f);
    p = fmaf(p, wv, -4.39150654e-06f);
    p = fmaf(p, wv, 0.00021858087f);
    p = fmaf(p, wv, -0.00125372503f);
    p = fmaf(p, wv, -0.00417768164f);
    p = fmaf(p, wv, 0.246640727f);
    p = fmaf(p, wv, 1.50140941f);
  } else {
    wv = sqrtf(wv) - 3.0f;
    p = -0.000200214257f;
    p = fmaf(p, wv, 0.000100950558f);
    p = fmaf(p, wv, 0.00134934322f);
    p = fmaf(p, wv, -0.00367342844f);
    p = fmaf(p, wv, 0.00573950773f);
    p = fmaf(p, wv, -0.0076224613f);
    p = fmaf(p, wv, 0.00943887047f);
    p = fmaf(p, wv, 1.00167406f);
    p = fmaf(p, wv, 2.83297682f);
  }
  return 1.4142135381698608f * (p * u);    // f32(sqrt(2)) * erfinv(u)
}

// ---- GEMM 2: mu = a2 @ Wmu + bmu, f32 out via LDS-staged full-line stores ----
__global__ __launch_bounds__(256, 5) void gemm2_kernel(const unsigned short* __restrict__ A2b,
    const unsigned short* __restrict__ Bt, const float* __restrict__ bias,
    float* __restrict__ OUT, int N, int sa, int sliced){
  __shared__ float sml[16][260];        // 16640 B
  int r0 = blockIdx.x * 32;
  int lane = threadIdx.x & 63;
  int nw = threadIdx.x >> 6;
  int lr = lane & 15, kg = lane >> 4;
  size_t sl = (size_t)N * 32;
  f32x4 acc[2][4] = {};
  for (int ks = 0; ks < 8; ++ks){
    int kb = ks*32 + kg*8;
    bf16x8 af[2];
    #pragma unroll
    for (int rf = 0; rf < 2; ++rf){
      int row = r0 + rf*16 + lr; if (row > N-1) row = N-1;
      size_t aoff = sliced ? ((size_t)ks*sl + (size_t)row*32 + kg*8)
                           : ((size_t)row*sa + kb);
      af[rf] = *(const bf16x8*)(A2b + aoff);
    }
    #pragma unroll
    for (int cf = 0; cf < 4; ++cf){
      int c = nw*64 + cf*16 + lr;
      bf16x8 bfr = *(const bf16x8*)(Bt + (size_t)c*HID + kb);
      acc[0][cf] = __builtin_amdgcn_mfma_f32_16x16x32_bf16(af[0], bfr, acc[0][cf], 0, 0, 0);
      acc[1][cf] = __builtin_amdgcn_mfma_f32_16x16x32_bf16(af[1], bfr, acc[1][cf], 0, 0, 0);
    }
  }
  f32x4 b4 = *(const f32x4*)(bias + lane*4);
  for (int rf = 0; rf < 2; ++rf){
    #pragma unroll
    for (int cf = 0; cf < 4; ++cf){
      int c = nw*64 + cf*16 + lr;
      #pragma unroll
      for (int i = 0; i < 4; ++i) sml[kg*4 + i][c] = acc[rf][cf][i];
    }
    __syncthreads();
    #pragma unroll
    for (int rr = 0; rr < 4; ++rr){
      int rl = nw*4 + rr;
      int row = r0 + rf*16 + rl;
      if (row < N){
        f32x4 m4 = *(const f32x4*)&sml[rl][lane*4];
        m4 += b4;
        __builtin_nontemporal_store(m4, (f32x4*)(OUT + (size_t)row*HID + lane*4));
      }
    }
    __syncthreads();
  }
}

// ---- GEMM 3: ls = a2 @ Wls + bls; reads back MU, fused reparam z ----
__global__ __launch_bounds__(256, 5) void gemm3_kernel(const unsigned short* __restrict__ A2b,
    const unsigned short* __restrict__ Bt, const float* __restrict__ bias,
    const float* __restrict__ MU, float* __restrict__ Z, float* __restrict__ LS,
    int N, int sa, int sliced){
  __shared__ float sml[16][260];        // 16640 B
  int r0 = blockIdx.x * 32;
  int lane = threadIdx.x & 63;
  int nw = threadIdx.x >> 6;
  int lr = lane & 15, kg = lane >> 4;
  size_t sl = (size_t)N * 32;
  f32x4 acc[2][4] = {};
  for (int ks = 0; ks < 8; ++ks){
    int kb = ks*32 + kg*8;
    bf16x8 af[2];
    #pragma unroll
    for (int rf = 0; rf < 2; ++rf){
      int row = r0 + rf*16 + lr; if (row > N-1) row = N-1;
      size_t aoff = sliced ? ((size_t)ks*sl + (size_t)row*32 + kg*8)
                           : ((size_t)row*sa + kb);
      af[rf] = *(const bf16x8*)(A2b + aoff);
    }
    #pragma unroll
    for (int cf = 0; cf < 4; ++cf){
      int c = nw*64 + cf*16 + lr;
      bf16x8 bfr = *(const bf16x8*)(Bt + (size_t)c*HID + kb);
      acc[0][cf] = __builtin_amdgcn_mfma_f32_16x16x32_bf16(af[0], bfr, acc[0][cf], 0, 0, 0);
      acc[1][cf] = __builtin_amdgcn_mfma_f32_16x16x32_bf16(af[1], bfr, acc[1][cf], 0, 0, 0);
    }
  }
  f32x4 b4 = *(const f32x4*)(bias + lane*4);
  for (int rf = 0; rf < 2; ++rf){
    #pragma unroll
    for (int cf = 0; cf < 4; ++cf){
      int c = nw*64 + cf*16 + lr;
      #pragma unroll
      for (int i = 0; i < 4; ++i) sml[kg*4 + i][c] = acc[rf][cf][i];
    }
    __syncthreads();
    #pragma unroll
    for (int rr = 0; rr < 4; ++rr){
      int rl = nw*4 + rr;
      int row = r0 + rf*16 + rl;
      if (row < N){
        size_t base = (size_t)row*HID + lane*4;
        f32x4 l4 = *(const f32x4*)&sml[rl][lane*4];
        l4 += b4;
        f32x4 m4 = *(const f32x4*)(MU + base);
        f32x4 z4;
        #pragma unroll
        for (int j = 0; j < 4; ++j){
          float e = gauss_eps((unsigned int)(base + j));
          float s = __builtin_amdgcn_exp2f(l4[j] * 1.44269504f);
          z4[j] = fmaf(s, e, m4[j]);
        }
        __builtin_nontemporal_store(z4, (f32x4*)(Z  + base));
        __builtin_nontemporal_store(l4, (f32x4*)(LS + base));
      }
    }
    __syncthreads();
  }
}

extern "C" void kernel_launch(void* const* d_in, const int* in_sizes, int n_in,
                              void* d_out, int out_size, void* d_ws, size_t ws_size,
                              hipStream_t stream){
  const float* x   = (const float*)d_in[0];
  const int*   ei  = (const int*)d_in[1];
  const float* W1  = (const float*)d_in[2];
  const float* b1  = (const float*)d_in[3];
  const float* Wmu = (const float*)d_in[4];
  const float* bmu = (const float*)d_in[5];
  const float* Wls = (const float*)d_in[6];
  const float* bls = (const float*)d_in[7];
  const int N = in_sizes[0] / HID;
  const int E = in_sizes[1] / 2;
  const size_t NA = ((size_t)N + 64) & ~(size_t)63;   // >= N+1, 64-aligned

  int* deg      = (int*)d_ws;
  int* fill     = deg + NA;
  int* rowptr   = fill + NA;
  int* partials = rowptr + NA;
  float* dinv   = (float*)(partials + 1024);
  int2* ew      = (int2*)(dinv + NA);                       // E pairs (col, wgt)
  unsigned short* Wt = (unsigned short*)(ew + (size_t)E);   // 3 * 65536 bf16
  unsigned short* a2ws = Wt + 3*65536;                      // packed sliced a2

  float* Z  = (float*)d_out;
  float* MU = Z + (size_t)N*HID;
  float* LS = MU + (size_t)N*HID;
  unsigned short* hb  = (unsigned short*)Z;                  // h (bf16, permuted), Z 1st half
  unsigned short* xb  = (unsigned short*)Z + (size_t)N*HID;  // x (bf16), Z 2nd half
  unsigned short* a1b = (unsigned short*)MU;                 // a1 (bf16, SLICED) in mu region

  // a2 placement: sliced in ws if it fits, else full-row stride-512 in LS region
  size_t ws_used = (size_t)((char*)a2ws - (char*)d_ws);
  bool packed = (ws_size >= ws_used + (size_t)N * 256 * sizeof(unsigned short));
  unsigned short* a2b = packed ? a2ws : (unsigned short*)LS;
  int sa = packed ? 256 : 512;
  int sliced2 = packed ? 1 : 0;

  hipMemsetAsync(deg, 0, NA*2*sizeof(int), stream);      // deg + fill

  int ebl = (E + 255)/256, nbl = (N + 255)/256;
  count_kernel  <<<ebl, 256, 0, stream>>>(ei, E, deg);
  dinv_kernel   <<<nbl, 256, 0, stream>>>(deg, dinv, N);
  scan1_kernel  <<<nbl, 256, 0, stream>>>(deg, rowptr, partials, N);
  scan2_kernel  <<<1,   256, 0, stream>>>(partials, nbl);
  scan3_kernel  <<<nbl, 256, 0, stream>>>(rowptr, partials, N, E);
  scatter_kernel<<<ebl, 256, 0, stream>>>(ei, E, rowptr, fill, dinv, ew);
  convW_kernel  <<<768, 256, 0, stream>>>(W1, Wmu, Wls, Wt);
  convX_kernel  <<<(N*HID/8 + 255)/256, 256, 0, stream>>>(x, xb, N*HID/8);

  int abl = ((N + 3)/4) * 8;             // (node-group) x 8 slices
  agg_slice   <<<abl, 256, 0, stream>>>(xb, a1b, rowptr, ew, dinv, N, 256);
  gemm1_kernel<<<(N + 31)/32, 256, 0, stream>>>(a1b, Wt, b1, hb, N);
  if (packed){
    agg_slice <<<abl, 256, 0, stream>>>(hb, a2b, rowptr, ew, dinv, N, 256);
  } else {
    agg_full  <<<(N + 3)/4, 256, 0, stream>>>(hb, a2b, rowptr, ew, dinv, N, 256, sa);
  }
  gemm2_kernel<<<(N + 31)/32, 256, 0, stream>>>(a2b, Wt + 65536,   bmu, MU, N, sa, sliced2);
  gemm3_kernel<<<(N + 31)/32, 256, 0, stream>>>(a2b, Wt + 2*65536, bls, MU, Z, LS, N, sa, sliced2);
}

// Round 14
// 730.266 us; speedup vs baseline: 1.2106x; 1.2106x over previous
//
#include <hip/hip_runtime.h>
#include <stdint.h>

#define HID 256

typedef __bf16 bf16x8 __attribute__((ext_vector_type(8)));
typedef float  f32x4  __attribute__((ext_vector_type(4)));
typedef unsigned int uint4v __attribute__((ext_vector_type(4)));
typedef unsigned int uint2v __attribute__((ext_vector_type(2)));

__device__ __forceinline__ unsigned short f2bf(float f){
  unsigned int x = __float_as_uint(f);
  x += 0x7FFFu + ((x >> 16) & 1u);      // RNE
  return (unsigned short)(x >> 16);
}
__device__ __forceinline__ float bflo(unsigned int x){ return __uint_as_float(x << 16); }
__device__ __forceinline__ float bfhi(unsigned int x){ return __uint_as_float(x & 0xFFFF0000u); }
__device__ __forceinline__ bf16x8 ntload8(const unsigned short* p){
  uint4v t = __builtin_nontemporal_load((const uint4v*)p);
  return __builtin_bit_cast(bf16x8, t);
}

// ---------------- CSR build ----------------
__global__ void count_kernel(const int* __restrict__ ei, int E, int* __restrict__ deg){
  int e = blockIdx.x*256 + threadIdx.x;
  if (e < E) atomicAdd(&deg[ei[E + e]], 1);
}

// block-local exclusive prefix of deg + block totals; also writes dinv
__global__ void scan1_kernel(const int* __restrict__ deg, int* __restrict__ rowptr,
                             int* __restrict__ partials, float* __restrict__ dinv, int N){
  __shared__ int sm[256];
  int t = threadIdx.x;
  int i = blockIdx.x*256 + t;
  int v = (i < N) ? deg[i] : 0;
  if (i < N) dinv[i] = 1.0f / sqrtf((float)(v + 1));   // +1 self loop
  int acc = v;
  sm[t] = acc;
  __syncthreads();
  for (int off = 1; off < 256; off <<= 1){
    int add = (t >= off) ? sm[t - off] : 0;
    __syncthreads();
    acc += add;
    sm[t] = acc;
    __syncthreads();
  }
  if (i < N) rowptr[i] = acc - v;                 // exclusive, block-local
  if (t == 255) partials[blockIdx.x] = acc;       // block total
}

__global__ void scan2_kernel(int* __restrict__ partials, int nb){
  __shared__ int sm[256];
  int t = threadIdx.x;
  int v = (t < nb) ? partials[t] : 0;
  int acc = v;
  sm[t] = acc;
  __syncthreads();
  for (int off = 1; off < 256; off <<= 1){
    int add = (t >= off) ? sm[t - off] : 0;
    __syncthreads();
    acc += add;
    sm[t] = acc;
    __syncthreads();
  }
  if (t < nb) partials[t] = acc - v;              // exclusive block offsets
}

__global__ void scan3_kernel(int* __restrict__ rowptr, const int* __restrict__ partials,
                             int N, int E){
  int i = blockIdx.x*256 + threadIdx.x;
  if (i < N) rowptr[i] += partials[blockIdx.x];
  if (i == 0) rowptr[N] = E;
}

// builds interleaved edge metadata ew[p] = (src, wgt)
__global__ void scatter_kernel(const int* __restrict__ ei, int E, const int* __restrict__ rowptr,
                               int* __restrict__ fill, const float* __restrict__ dinv,
                               int2* __restrict__ ew){
  int e = blockIdx.x*256 + threadIdx.x;
  if (e >= E) return;
  int s = ei[e];
  int d = ei[E + e];
  int p = rowptr[d] + atomicAdd(&fill[d], 1);
  int2 v; v.x = s; v.y = __float_as_int(dinv[s] * dinv[d]);
  ew[p] = v;
}

// ---- merged: W -> Wt (bf16, transposed, pi-permuted K for m=1,2) + x -> xb ----
// pi(p) = (p&~63) | ((p&3)<<4) | ((p>>2)&15)  matches gemm1's packed H layout.
__global__ void convWX_kernel(const float* __restrict__ W1, const float* __restrict__ Wmu,
                              const float* __restrict__ Wls, unsigned short* __restrict__ Wt,
                              const float* __restrict__ x, unsigned short* __restrict__ xb,
                              int total8){
  int t = blockIdx.x*256 + threadIdx.x;
  if (t < 3*65536){
    int m = t >> 16;
    int r = t & 0xFFFF;
    int n = r >> 8, k = r & 255;
    int ksrc = (m == 0) ? k : ((k & ~63) | ((k & 3) << 4) | ((k >> 2) & 15));
    const float* W = (m == 0) ? W1 : (m == 1 ? Wmu : Wls);
    Wt[t] = f2bf(W[ksrc*HID + n]);                // Wt[m][n][k] = W[pi(k)][n]
    return;
  }
  t -= 3*65536;
  if (t >= total8) return;
  const float* p = x + (size_t)t*8;
  f32x4 a = *(const f32x4*)p;
  f32x4 b = *(const f32x4*)(p + 4);
  ushort4 o0, o1;
  o0.x = f2bf(a[0]); o0.y = f2bf(a[1]); o0.z = f2bf(a[2]); o0.w = f2bf(a[3]);
  o1.x = f2bf(b[0]); o1.y = f2bf(b[1]); o1.z = f2bf(b[2]); o1.w = f2bf(b[3]);
  ushort4* qq = (ushort4*)(xb + (size_t)t*8);
  qq[0] = o0; qq[1] = o1;
}

// -------- bf16 aggregation: one wave per dst node, quarter-wave, full row --------
// quarter q handles neighbor j+q; 16 lanes x 32B each (2 dwordx4 in flight).
// Edge metadata: NT-loaded (streamed once, don't evict gather-hot X lines),
// double-buffered across 64-edge batches.
__global__ void agg_bf16(const unsigned short* __restrict__ X, unsigned short* __restrict__ Y,
                         const int* __restrict__ rowptr, const int2* __restrict__ ew,
                         const float* __restrict__ dinv, int N, int sin, int sout){
  int w = (blockIdx.x * blockDim.x + threadIdx.x) >> 6;
  int lane = threadIdx.x & 63;
  if (w >= N) return;
  int q  = lane >> 4;
  int cl = lane & 15;
  float acc[16];
  #pragma unroll
  for (int k = 0; k < 16; ++k) acc[k] = 0.f;
  int p0 = rowptr[w], p1 = rowptr[w+1];
  int sc = 0; float wc = 0.f;
  {
    int idx = p0 + lane;
    if (idx < p1){ uint2v e = __builtin_nontemporal_load((const uint2v*)(ew + idx));
                   sc = (int)e.x; wc = __uint_as_float(e.y); }
  }
  for (int base = p0; base < p1; base += 64){
    int cur_s = sc; float cur_w = wc;
    // prefetch next metadata batch
    sc = 0; wc = 0.f;
    int nidx = base + 64 + lane;
    if (nidx < p1){ uint2v e = __builtin_nontemporal_load((const uint2v*)(ew + nidx));
                    sc = (int)e.x; wc = __uint_as_float(e.y); }
    int cnt = min(p1 - base, 64);
    for (int j = 0; j < cnt; j += 4){
      int   s = __shfl(cur_s, j + q);
      float f = __shfl(cur_w, j + q);
      const unsigned short* rp = X + (size_t)s*sin + cl*16;
      uint4v u0 = *(const uint4v*)rp;
      uint4v u1 = *(const uint4v*)(rp + 8);
      acc[ 0]=fmaf(bflo(u0.x),f,acc[ 0]); acc[ 1]=fmaf(bfhi(u0.x),f,acc[ 1]);
      acc[ 2]=fmaf(bflo(u0.y),f,acc[ 2]); acc[ 3]=fmaf(bfhi(u0.y),f,acc[ 3]);
      acc[ 4]=fmaf(bflo(u0.z),f,acc[ 4]); acc[ 5]=fmaf(bfhi(u0.z),f,acc[ 5]);
      acc[ 6]=fmaf(bflo(u0.w),f,acc[ 6]); acc[ 7]=fmaf(bfhi(u0.w),f,acc[ 7]);
      acc[ 8]=fmaf(bflo(u1.x),f,acc[ 8]); acc[ 9]=fmaf(bfhi(u1.x),f,acc[ 9]);
      acc[10]=fmaf(bflo(u1.y),f,acc[10]); acc[11]=fmaf(bfhi(u1.y),f,acc[11]);
      acc[12]=fmaf(bflo(u1.z),f,acc[12]); acc[13]=fmaf(bfhi(u1.z),f,acc[13]);
      acc[14]=fmaf(bflo(u1.w),f,acc[14]); acc[15]=fmaf(bfhi(u1.w),f,acc[15]);
    }
  }
  #pragma unroll
  for (int k = 0; k < 16; ++k){
    acc[k] += __shfl_xor(acc[k], 16);
    acc[k] += __shfl_xor(acc[k], 32);
  }
  if (q == 0){
    float s2 = dinv[w]; s2 *= s2;        // self loop
    const unsigned short* rp = X + (size_t)w*sin + cl*16;
    uint4v u0 = *(const uint4v*)rp;
    uint4v u1 = *(const uint4v*)(rp + 8);
    acc[ 0]=fmaf(bflo(u0.x),s2,acc[ 0]); acc[ 1]=fmaf(bfhi(u0.x),s2,acc[ 1]);
    acc[ 2]=fmaf(bflo(u0.y),s2,acc[ 2]); acc[ 3]=fmaf(bfhi(u0.y),s2,acc[ 3]);
    acc[ 4]=fmaf(bflo(u0.z),s2,acc[ 4]); acc[ 5]=fmaf(bfhi(u0.z),s2,acc[ 5]);
    acc[ 6]=fmaf(bflo(u0.w),s2,acc[ 6]); acc[ 7]=fmaf(bfhi(u0.w),s2,acc[ 7]);
    acc[ 8]=fmaf(bflo(u1.x),s2,acc[ 8]); acc[ 9]=fmaf(bfhi(u1.x),s2,acc[ 9]);
    acc[10]=fmaf(bflo(u1.y),s2,acc[10]); acc[11]=fmaf(bfhi(u1.y),s2,acc[11]);
    acc[12]=fmaf(bflo(u1.z),s2,acc[12]); acc[13]=fmaf(bfhi(u1.z),s2,acc[13]);
    acc[14]=fmaf(bflo(u1.w),s2,acc[14]); acc[15]=fmaf(bfhi(u1.w),s2,acc[15]);
    uint4v o0, o1;
    o0.x = (unsigned int)f2bf(acc[ 0]) | ((unsigned int)f2bf(acc[ 1]) << 16);
    o0.y = (unsigned int)f2bf(acc[ 2]) | ((unsigned int)f2bf(acc[ 3]) << 16);
    o0.z = (unsigned int)f2bf(acc[ 4]) | ((unsigned int)f2bf(acc[ 5]) << 16);
    o0.w = (unsigned int)f2bf(acc[ 6]) | ((unsigned int)f2bf(acc[ 7]) << 16);
    o1.x = (unsigned int)f2bf(acc[ 8]) | ((unsigned int)f2bf(acc[ 9]) << 16);
    o1.y = (unsigned int)f2bf(acc[10]) | ((unsigned int)f2bf(acc[11]) << 16);
    o1.z = (unsigned int)f2bf(acc[12]) | ((unsigned int)f2bf(acc[13]) << 16);
    o1.w = (unsigned int)f2bf(acc[14]) | ((unsigned int)f2bf(acc[15]) << 16);
    uint4v* yp = (uint4v*)(Y + (size_t)w*sout + cl*16);
    yp[0] = o0; yp[1] = o1;
  }
}

// ---------------- GEMM 1: h = relu(a1 @ W1 + b1), bf16 out, BM=32 ----------------
// H stored PERMUTED: position p = nw*64+lr*4+j holds column nw*64+j*16+lr.
__global__ __launch_bounds__(256, 8) void gemm1_kernel(const unsigned short* __restrict__ A,
    const unsigned short* __restrict__ Bt, const float* __restrict__ bias,
    unsigned short* __restrict__ H, int N){
  int r0 = blockIdx.x * 32;
  int lane = threadIdx.x & 63;
  int nw = threadIdx.x >> 6;
  int lr = lane & 15, kg = lane >> 4;
  f32x4 acc[2][4] = {};
  for (int ks = 0; ks < 8; ++ks){
    int kb = ks*32 + kg*8;
    bf16x8 af[2];
    #pragma unroll
    for (int rf = 0; rf < 2; ++rf){
      int row = r0 + rf*16 + lr; if (row > N-1) row = N-1;
      af[rf] = *(const bf16x8*)(A + (size_t)row*HID + kb);
    }
    #pragma unroll
    for (int cf = 0; cf < 4; ++cf){
      int c = nw*64 + cf*16 + lr;
      bf16x8 bfr = *(const bf16x8*)(Bt + (size_t)c*HID + kb);
      acc[0][cf] = __builtin_amdgcn_mfma_f32_16x16x32_bf16(af[0], bfr, acc[0][cf], 0, 0, 0);
      acc[1][cf] = __builtin_amdgcn_mfma_f32_16x16x32_bf16(af[1], bfr, acc[1][cf], 0, 0, 0);
    }
  }
  float bv[4];
  #pragma unroll
  for (int cf = 0; cf < 4; ++cf) bv[cf] = bias[nw*64 + cf*16 + lr];
  #pragma unroll
  for (int rf = 0; rf < 2; ++rf){
    #pragma unroll
    for (int i = 0; i < 4; ++i){
      int row = r0 + rf*16 + kg*4 + i;
      if (row < N){
        ushort4 o;
        o.x = f2bf(fmaxf(acc[rf][0][i] + bv[0], 0.0f));
        o.y = f2bf(fmaxf(acc[rf][1][i] + bv[1], 0.0f));
        o.z = f2bf(fmaxf(acc[rf][2][i] + bv[2], 0.0f));
        o.w = f2bf(fmaxf(acc[rf][3][i] + bv[3], 0.0f));
        *(ushort4*)(H + (size_t)row*HID + nw*64 + lr*4) = o;
      }
    }
  }
}

// ---- eps: JAX PARTITIONABLE threefry2x32 (key=(0,1)) + XLA erfinv ----
__device__ __forceinline__ unsigned int rotl32(unsigned int v, int r){
  return (v << r) | (v >> (32 - r));
}

__device__ __forceinline__ float gauss_eps(unsigned int idxv){
  unsigned int x0 = 0u, x1 = idxv;
  const unsigned int ks0 = 0u, ks1 = 1u, ks2 = 0x1BD11BDAu ^ 0u ^ 1u;
  x0 += ks0; x1 += ks1;
#define TFR(r) { x0 += x1; x1 = rotl32(x1, r); x1 ^= x0; }
  TFR(13) TFR(15) TFR(26) TFR(6)   x0 += ks1; x1 += ks2 + 1u;
  TFR(17) TFR(29) TFR(16) TFR(24)  x0 += ks2; x1 += ks0 + 2u;
  TFR(13) TFR(15) TFR(26) TFR(6)   x0 += ks0; x1 += ks1 + 3u;
  TFR(17) TFR(29) TFR(16) TFR(24)  x0 += ks1; x1 += ks2 + 4u;
  TFR(13) TFR(15) TFR(26) TFR(6)   x0 += ks2; x1 += ks0 + 5u;
#undef TFR
  unsigned int bits = x0 ^ x1;                                   // 32-bit fold
  float f = __uint_as_float((bits >> 9) | 0x3F800000u) - 1.0f;   // [0,1)
  const float lo = -0.99999994f;                                  // nextafter(-1,0)
  float u = fmaxf(lo, fmaf(f, 2.0f, lo));                         // (hi-lo)==2.0f exactly
  float t = fmaf(-u, u, 1.0f);
  float wv = -0.69314718056f * __builtin_amdgcn_logf(t);
  float p;
  if (wv < 5.0f){
    wv -= 2.5f;
    p = 2.81022636e-08f;
    p = fmaf(p, wv, 3.43273939e-07f);
    p = fmaf(p, wv, -3.5233877e-06f);
    p = fmaf(p, wv, -4.39150654e-06f);
    p = fmaf(p, wv, 0.00021858087f);
    p = fmaf(p, wv, -0.00125372503f);
    p = fmaf(p, wv, -0.00417768164f);
    p = fmaf(p, wv, 0.246640727f);
    p = fmaf(p, wv, 1.50140941f);
  } else {
    wv = sqrtf(wv) - 3.0f;
    p = -0.000200214257f;
    p = fmaf(p, wv, 0.000100950558f);
    p = fmaf(p, wv, 0.00134934322f);
    p = fmaf(p, wv, -0.00367342844f);
    p = fmaf(p, wv, 0.00573950773f);
    p = fmaf(p, wv, -0.0076224613f);
    p = fmaf(p, wv, 0.00943887047f);
    p = fmaf(p, wv, 1.00167406f);
    p = fmaf(p, wv, 2.83297682f);
  }
  return 1.4142135381698608f * (p * u);    // f32(sqrt(2)) * erfinv(u)
}

// ---- GEMM 2: mu = a2 @ Wmu + bmu, f32 out via LDS-staged full-line stores ----
__global__ __launch_bounds__(256, 5) void gemm2_kernel(const unsigned short* __restrict__ A2b,
    const unsigned short* __restrict__ Bt, const float* __restrict__ bias,
    float* __restrict__ OUT, int N, int sa){
  __shared__ float sml[16][260];        // 16640 B
  int r0 = blockIdx.x * 32;
  int lane = threadIdx.x & 63;
  int nw = threadIdx.x >> 6;
  int lr = lane & 15, kg = lane >> 4;
  f32x4 acc[2][4] = {};
  for (int ks = 0; ks < 8; ++ks){
    int kb = ks*32 + kg*8;
    bf16x8 af[2];
    #pragma unroll
    for (int rf = 0; rf < 2; ++rf){
      int row = r0 + rf*16 + lr; if (row > N-1) row = N-1;
      af[rf] = ntload8(A2b + (size_t)row*sa + kb);
    }
    #pragma unroll
    for (int cf = 0; cf < 4; ++cf){
      int c = nw*64 + cf*16 + lr;
      bf16x8 bfr = *(const bf16x8*)(Bt + (size_t)c*HID + kb);
      acc[0][cf] = __builtin_amdgcn_mfma_f32_16x16x32_bf16(af[0], bfr, acc[0][cf], 0, 0, 0);
      acc[1][cf] = __builtin_amdgcn_mfma_f32_16x16x32_bf16(af[1], bfr, acc[1][cf], 0, 0, 0);
    }
  }
  f32x4 b4 = *(const f32x4*)(bias + lane*4);
  for (int rf = 0; rf < 2; ++rf){
    #pragma unroll
    for (int cf = 0; cf < 4; ++cf){
      int c = nw*64 + cf*16 + lr;
      #pragma unroll
      for (int i = 0; i < 4; ++i) sml[kg*4 + i][c] = acc[rf][cf][i];
    }
    __syncthreads();
    #pragma unroll
    for (int rr = 0; rr < 4; ++rr){
      int rl = nw*4 + rr;
      int row = r0 + rf*16 + rl;
      if (row < N){
        f32x4 m4 = *(const f32x4*)&sml[rl][lane*4];
        m4 += b4;
        __builtin_nontemporal_store(m4, (f32x4*)(OUT + (size_t)row*HID + lane*4));
      }
    }
    __syncthreads();
  }
}

// ---- GEMM 3: ls = a2 @ Wls + bls; reads back MU (NT), fused reparam z ----
__global__ __launch_bounds__(256, 5) void gemm3_kernel(const unsigned short* __restrict__ A2b,
    const unsigned short* __restrict__ Bt, const float* __restrict__ bias,
    const float* __restrict__ MU, float* __restrict__ Z, float* __restrict__ LS,
    int N, int sa){
  __shared__ float sml[16][260];        // 16640 B
  int r0 = blockIdx.x * 32;
  int lane = threadIdx.x & 63;
  int nw = threadIdx.x >> 6;
  int lr = lane & 15, kg = lane >> 4;
  f32x4 acc[2][4] = {};
  for (int ks = 0; ks < 8; ++ks){
    int kb = ks*32 + kg*8;
    bf16x8 af[2];
    #pragma unroll
    for (int rf = 0; rf < 2; ++rf){
      int row = r0 + rf*16 + lr; if (row > N-1) row = N-1;
      af[rf] = ntload8(A2b + (size_t)row*sa + kb);
    }
    #pragma unroll
    for (int cf = 0; cf < 4; ++cf){
      int c = nw*64 + cf*16 + lr;
      bf16x8 bfr = *(const bf16x8*)(Bt + (size_t)c*HID + kb);
      acc[0][cf] = __builtin_amdgcn_mfma_f32_16x16x32_bf16(af[0], bfr, acc[0][cf], 0, 0, 0);
      acc[1][cf] = __builtin_amdgcn_mfma_f32_16x16x32_bf16(af[1], bfr, acc[1][cf], 0, 0, 0);
    }
  }
  f32x4 b4 = *(const f32x4*)(bias + lane*4);
  for (int rf = 0; rf < 2; ++rf){
    #pragma unroll
    for (int cf = 0; cf < 4; ++cf){
      int c = nw*64 + cf*16 + lr;
      #pragma unroll
      for (int i = 0; i < 4; ++i) sml[kg*4 + i][c] = acc[rf][cf][i];
    }
    __syncthreads();
    #pragma unroll
    for (int rr = 0; rr < 4; ++rr){
      int rl = nw*4 + rr;
      int row = r0 + rf*16 + rl;
      if (row < N){
        size_t base = (size_t)row*HID + lane*4;
        f32x4 l4 = *(const f32x4*)&sml[rl][lane*4];
        l4 += b4;
        f32x4 m4 = __builtin_nontemporal_load((const f32x4*)(MU + base));
        f32x4 z4;
        #pragma unroll
        for (int j = 0; j < 4; ++j){
          float e = gauss_eps((unsigned int)(base + j));
          float s = __builtin_amdgcn_exp2f(l4[j] * 1.44269504f);
          z4[j] = fmaf(s, e, m4[j]);
        }
        __builtin_nontemporal_store(z4, (f32x4*)(Z  + base));
        __builtin_nontemporal_store(l4, (f32x4*)(LS + base));
      }
    }
    __syncthreads();
  }
}

extern "C" void kernel_launch(void* const* d_in, const int* in_sizes, int n_in,
                              void* d_out, int out_size, void* d_ws, size_t ws_size,
                              hipStream_t stream){
  const float* x   = (const float*)d_in[0];
  const int*   ei  = (const int*)d_in[1];
  const float* W1  = (const float*)d_in[2];
  const float* b1  = (const float*)d_in[3];
  const float* Wmu = (const float*)d_in[4];
  const float* bmu = (const float*)d_in[5];
  const float* Wls = (const float*)d_in[6];
  const float* bls = (const float*)d_in[7];
  const int N = in_sizes[0] / HID;
  const int E = in_sizes[1] / 2;
  const size_t NA = ((size_t)N + 64) & ~(size_t)63;   // >= N+1, 64-aligned

  int* deg      = (int*)d_ws;
  int* fill     = deg + NA;
  int* rowptr   = fill + NA;
  int* partials = rowptr + NA;
  float* dinv   = (float*)(partials + 1024);
  int2* ew      = (int2*)(dinv + NA);                       // E pairs (src, wgt)
  unsigned short* Wt = (unsigned short*)(ew + (size_t)E);   // 3 * 65536 bf16
  unsigned short* a2ws = Wt + 3*65536;                      // packed a2 candidate

  float* Z  = (float*)d_out;
  float* MU = Z + (size_t)N*HID;
  float* LS = MU + (size_t)N*HID;
  unsigned short* hb  = (unsigned short*)Z;                  // h (bf16, permuted), Z 1st half
  unsigned short* xb  = (unsigned short*)Z + (size_t)N*HID;  // x (bf16), Z 2nd half
  unsigned short* a1b = (unsigned short*)MU;                 // a1 (bf16) in mu region

  // a2 placement: packed in ws if it fits, else stride-512 rows in LS region
  size_t ws_used = (size_t)((char*)a2ws - (char*)d_ws);
  bool packed = (ws_size >= ws_used + (size_t)N * 256 * sizeof(unsigned short));
  unsigned short* a2b = packed ? a2ws : (unsigned short*)LS;
  int sa = packed ? 256 : 512;

  hipMemsetAsync(deg, 0, NA*2*sizeof(int), stream);      // deg + fill

  int ebl = (E + 255)/256, nbl = (N + 255)/256;
  int total8 = N*HID/8;
  count_kernel  <<<ebl, 256, 0, stream>>>(ei, E, deg);
  scan1_kernel  <<<nbl, 256, 0, stream>>>(deg, rowptr, partials, dinv, N);
  scan2_kernel  <<<1,   256, 0, stream>>>(partials, nbl);
  scan3_kernel  <<<nbl, 256, 0, stream>>>(rowptr, partials, N, E);
  scatter_kernel<<<ebl, 256, 0, stream>>>(ei, E, rowptr, fill, dinv, ew);
  convWX_kernel <<<(3*65536 + total8 + 255)/256, 256, 0, stream>>>(W1, Wmu, Wls, Wt, x, xb, total8);

  agg_bf16    <<<(N + 3)/4,  256, 0, stream>>>(xb, a1b, rowptr, ew, dinv, N, 256, 256);
  gemm1_kernel<<<(N + 31)/32, 256, 0, stream>>>(a1b, Wt, b1, hb, N);
  agg_bf16    <<<(N + 3)/4,  256, 0, stream>>>(hb, a2b, rowptr, ew, dinv, N, 256, sa);
  gemm2_kernel<<<(N + 31)/32, 256, 0, stream>>>(a2b, Wt + 65536,   bmu, MU, N, sa);
  gemm3_kernel<<<(N + 31)/32, 256, 0, stream>>>(a2b, Wt + 2*65536, bls, MU, Z, LS, N, sa);
}